// Round 9
// baseline (2247.633 us; speedup 1.0000x reference)
//
#include <hip/hip_runtime.h>
#include <math.h>

// TransformersLSTM: T=512, I=512, H=1024, L=512, O=1.
// Split-grid persistent kernel: blocks 0..127 encoder, 128..255 decoder.
// Weights VGPR-resident. Tagless handoff on 0xAA-poisoned write-once buffers.
// R9 = R8 + XCD-relay broadcast: blocks discover their XCD (s_getreg XCC_ID,
// HW-verified) + per-XCD slot (atomic). Slot-0 encoder/decoder block per XCD
// relays eh/dh granules from the LLC buffer into an XCD-local region (sc0
// stores -> own L2); all other blocks poll locally (sc0 loads, L2 hits, no
// fabric traffic). Tests the congestion hypothesis: R6 (per-line) and R8
// (sampling period) are falsified; 16x less uncached LLC poll traffic is the
// remaining lever. Sticky per-block fallback to direct LLC polling keeps
// correctness independent of block->XCD mapping; kernel-start agent-acquire
// fence (buffer_inv) kills cross-replay L2 staleness; degrades to R8 if ws
// is too small for the local regions.

#define T_STEPS 512
#define ENC_BLK 128
#define NBLK    256
#define NTHR    512
#define POLL_LIMIT 30000u
#define LOC_LIMIT  1024u
#define REPSZ ((size_t)T_STEPS * 1024)

typedef float fv4 __attribute__((ext_vector_type(4)));

__device__ __forceinline__ float sigf(float x) { return 1.0f / (1.0f + expf(-x)); }

// 4B cache-bypass store to LLC (device-visible).
__device__ __forceinline__ void st_llc4(float* p, float v) {
  asm volatile("global_store_dword %0, %1, off sc0 sc1" :: "v"(p), "v"(v) : "memory");
}
// 4B / 16B L2-scope stores (XCD-local region).
__device__ __forceinline__ void st_loc4(float* p, float v) {
  asm volatile("global_store_dword %0, %1, off sc0" :: "v"(p), "v"(v) : "memory");
}
__device__ __forceinline__ void st_loc16(float* p, fv4 v) {
  asm volatile("global_store_dwordx4 %0, %1, off sc0" :: "v"(p), "v"(v) : "memory");
}

__device__ __forceinline__ bool valid4(fv4 v) {
  return __float_as_uint(v.x) != 0xAAAAAAAAu && __float_as_uint(v.y) != 0xAAAAAAAAu &&
         __float_as_uint(v.z) != 0xAAAAAAAAu && __float_as_uint(v.w) != 0xAAAAAAAAu;
}

// 2-deep pipelined poison-poll, LLC path (sc0 sc1).
__device__ __forceinline__ fv4 poll2_llc(const float* p, unsigned limit, int* okp) {
  fv4 a, b;
  int ok = 1;
  asm volatile("global_load_dwordx4 %0, %1, off sc0 sc1" : "=v"(a) : "v"(p) : "memory");
  for (unsigned it = 0;; ++it) {
    asm volatile("global_load_dwordx4 %0, %1, off sc0 sc1" : "=v"(b) : "v"(p) : "memory");
    asm volatile("s_waitcnt vmcnt(1)" : "+v"(a) :: "memory");
    if (valid4(a)) { asm volatile("s_waitcnt vmcnt(0)" ::: "memory"); break; }
    asm volatile("global_load_dwordx4 %0, %1, off sc0 sc1" : "=v"(a) : "v"(p) : "memory");
    asm volatile("s_waitcnt vmcnt(1)" : "+v"(b) :: "memory");
    if (valid4(b)) { asm volatile("s_waitcnt vmcnt(0)" ::: "memory"); a = b; break; }
    if (it > limit) { ok = 0; asm volatile("s_waitcnt vmcnt(0)" ::: "memory"); break; }
  }
  *okp = ok;
  return a;
}
// 2-deep pipelined poison-poll, XCD-local path (sc0 only -> own L2).
__device__ __forceinline__ fv4 poll2_loc(const float* p, unsigned limit, int* okp) {
  fv4 a, b;
  int ok = 1;
  asm volatile("global_load_dwordx4 %0, %1, off sc0" : "=v"(a) : "v"(p) : "memory");
  for (unsigned it = 0;; ++it) {
    asm volatile("global_load_dwordx4 %0, %1, off sc0" : "=v"(b) : "v"(p) : "memory");
    asm volatile("s_waitcnt vmcnt(1)" : "+v"(a) :: "memory");
    if (valid4(a)) { asm volatile("s_waitcnt vmcnt(0)" ::: "memory"); break; }
    asm volatile("global_load_dwordx4 %0, %1, off sc0" : "=v"(a) : "v"(p) : "memory");
    asm volatile("s_waitcnt vmcnt(1)" : "+v"(b) :: "memory");
    if (valid4(b)) { asm volatile("s_waitcnt vmcnt(0)" ::: "memory"); a = b; break; }
    if (it > limit) { ok = 0; asm volatile("s_waitcnt vmcnt(0)" ::: "memory"); break; }
  }
  *okp = ok;
  return a;
}
// consumer: local first (sticky fallback to LLC if region never fills).
__device__ __forceinline__ fv4 poll_any(const float* ploc, const float* pllc,
                                        int* sfall, int* okp) {
  if (!*sfall) {
    int ok1;
    const fv4 v = poll2_loc(ploc, LOC_LIMIT, &ok1);
    if (ok1) { *okp = 1; return v; }
    *sfall = 1;  // idempotent LDS write; mapping broken -> go direct from now on
  }
  return poll2_llc(pllc, POLL_LIMIT, okp);
}

// ------------- precompute PX = W_ih_e @ x_t + b_ih_e + b_hh_e -----------------
// px[(t*1024 + h)*4 + g] for gate row r = g*1024 + h. Also zeroes XCD counters.
__global__ __launch_bounds__(256) void prep_gemm(const float* __restrict__ X,
                                                 const float* __restrict__ Wih,
                                                 const float* __restrict__ bih,
                                                 const float* __restrict__ bhh,
                                                 float* __restrict__ px,
                                                 int* ctrs) {
  if (blockIdx.x == 0 && blockIdx.y == 0 && threadIdx.x < 16) ctrs[threadIdx.x] = 0;
  __shared__ float Ws[64][68];
  __shared__ float Xs[64][68];
  const int r0 = blockIdx.x * 64;
  const int t0 = blockIdx.y * 64;
  const int tid = threadIdx.x;
  const int tr = tid & 15;
  const int tc = tid >> 4;
  float acc[4][4] = {{0.f}};
  for (int k0 = 0; k0 < 512; k0 += 64) {
    __syncthreads();
    const int lr = tid >> 4;
    const int lc = (tid & 15) * 4;
#pragma unroll
    for (int rep = 0; rep < 4; rep++) {
      const int row = lr + rep * 16;
      const float4 wv = *(const float4*)&Wih[(size_t)(r0 + row) * 512 + k0 + lc];
      Ws[lc + 0][row] = wv.x; Ws[lc + 1][row] = wv.y;
      Ws[lc + 2][row] = wv.z; Ws[lc + 3][row] = wv.w;
      const float4 xv = *(const float4*)&X[(size_t)(t0 + row) * 512 + k0 + lc];
      Xs[row][lc + 0] = xv.x; Xs[row][lc + 1] = xv.y;
      Xs[row][lc + 2] = xv.z; Xs[row][lc + 3] = xv.w;
    }
    __syncthreads();
    for (int kk = 0; kk < 64; kk++) {
      float a[4], x[4];
#pragma unroll
      for (int i = 0; i < 4; i++) a[i] = Ws[kk][tr * 4 + i];
#pragma unroll
      for (int j = 0; j < 4; j++) x[j] = Xs[tc * 4 + j][kk];
#pragma unroll
      for (int i = 0; i < 4; i++)
#pragma unroll
        for (int j = 0; j < 4; j++) acc[i][j] += a[i] * x[j];
    }
  }
#pragma unroll
  for (int i = 0; i < 4; i++) {
    const int r = r0 + tr * 4 + i;
    const int g = r >> 10, h = r & 1023;
    const float bsum = bih[r] + bhh[r];
#pragma unroll
    for (int j = 0; j < 4; j++) {
      const int t = t0 + tc * 4 + j;
      px[((size_t)t * 1024 + h) * 4 + g] = acc[i][j] + bsum;
    }
  }
}

// ------------------------------ persistent kernel -----------------------------
// 512 threads: wave w (0..7) owns gate g=w>>1, h-rows j=(w&1)*4+ri (ri=lane&3);
// lane s16=lane>>2 covers K in [s16*64, s16*64+64) as 16 float4 (rot by s16).
__global__ __launch_bounds__(512, 1) void lstm_persist(
    const float* __restrict__ Whhe, const float* __restrict__ Wattn,
    const float* __restrict__ battn, const float* __restrict__ Wihd,
    const float* __restrict__ Whhd, const float* __restrict__ bihd,
    const float* __restrict__ bhhd, const float* __restrict__ Wout,
    const float* __restrict__ bout, const float* __restrict__ px,
    float* ehbuf, float* dhbuf, float* ehloc, float* dhloc, int* ctrs,
    int use_loc, float* out) {
  __shared__ float4 xbuf[256];   // eh copy (both groups)
  __shared__ float4 dbuf[256];   // dh copy (decoder)
  __shared__ float  aw[512];     // softmax state (decoder)
  __shared__ float  GA[32];      // gate sums (enc ge / dec g1)
  __shared__ float  GB[32];      // dec g2
  __shared__ float  bd[32];      // decoder bias
  __shared__ float  redE[4];     // energy (eh part)
  __shared__ float  redE2[4];    // energy (dh part)
  __shared__ float  red[8];      // softmax sums (8 waves)
  __shared__ float  red2[4];     // out-dot reduce
  __shared__ int    sbad;
  __shared__ int    s_slot;
  __shared__ int    sfallE;      // sticky fallback flags
  __shared__ int    sfallD;

  const int b    = blockIdx.x;
  const int tid  = threadIdx.x;
  const int w    = tid >> 6;
  const int lane = tid & 63;
  const int ri   = lane & 3;    // row-in-wave
  const int s16  = lane >> 2;   // K-segment 0..15 (64 floats)
  const int g    = w >> 1;      // gate index
  const int j    = ((w & 1) << 2) + ri;  // h-row within block's 8

  // --- XCD discovery + cross-replay L2 invalidate ---
  __builtin_amdgcn_fence(__ATOMIC_ACQUIRE, "agent");  // buffer_inv, once
  unsigned xcd;
  asm volatile("s_getreg_b32 %0, hwreg(HW_REG_XCC_ID)" : "=s"(xcd));
  xcd &= 7u;
  if (tid == 0) {
    sbad = 0;
    sfallE = use_loc ? 0 : 1;
    sfallD = use_loc ? 0 : 1;
    int* ctr = (b < ENC_BLK) ? &ctrs[xcd] : &ctrs[8 + xcd];
    s_slot = use_loc ? atomicAdd(ctr, 1) : 1;
  }
  float* myeloc = ehloc + (size_t)xcd * REPSZ;
  float* mydloc = dhloc + (size_t)xcd * REPSZ;

  if (b < ENC_BLK) {
    // =========================== encoder group ===============================
    const int e = b;
    const int r = (g << 10) + (e << 3) + j;  // owned gate row
    float4 we[16];
#pragma unroll
    for (int k = 0; k < 16; k++) {
      const int m = (k + s16) & 15;
      we[k] = *(const float4*)&Whhe[(size_t)r * 1024 + s16 * 64 + m * 4];
    }
    if (tid < 256) xbuf[tid] = make_float4(0.f, 0.f, 0.f, 0.f);
    float ec = 0.f;  // cell state (tid<8)
    __syncthreads();
    const bool relay = (s_slot == 0);  // eh-relay for this XCD

    for (int t = 0; t < T_STEPS; t++) {
      float ge = 0.f;
#pragma unroll
      for (int k = 0; k < 16; k++) {
        const int m = (k + s16) & 15;
        const float4 x = xbuf[s16 * 16 + m];
        ge += we[k].x * x.x + we[k].y * x.y + we[k].z * x.z + we[k].w * x.w;
      }
      if (s16 == 0) ge += px[((size_t)t * 1024 + (e << 3) + j) * 4 + g];
      ge += __shfl_xor(ge, 4, 64);
      ge += __shfl_xor(ge, 8, 64);
      ge += __shfl_xor(ge, 16, 64);
      ge += __shfl_xor(ge, 32, 64);
      if (lane < 4) GA[w * 4 + lane] = ge;  // GA[g*8+j]
      __syncthreads();  // S1
      if (tid < 8) {
        const float gi = GA[tid], gf = GA[8 + tid], gg = GA[16 + tid], go = GA[24 + tid];
        const float c = sigf(gf) * ec + sigf(gi) * tanhf(gg);
        ec = c;
        const float h = sigf(go) * tanhf(c);
        st_llc4(&ehbuf[(size_t)t * 1024 + (e << 3) + tid], h);  // coalesced 32B
        if (use_loc) st_loc4(&myeloc[(size_t)t * 1024 + (e << 3) + tid], h);
      }
      int ok = 1;
      if (tid < 256) {
        const float* pllc = &ehbuf[(size_t)t * 1024 + tid * 4];
        fv4 ev;
        if (relay && use_loc) {
          ev = poll2_llc(pllc, POLL_LIMIT, &ok);
          st_loc16(&myeloc[(size_t)t * 1024 + tid * 4], ev);  // forward to own L2
        } else {
          ev = poll_any(&myeloc[(size_t)t * 1024 + tid * 4], pllc, &sfallE, &ok);
        }
        xbuf[tid] = make_float4(ev.x, ev.y, ev.z, ev.w);
      }
      if (!ok) sbad = 1;
      __syncthreads();  // S2
      if (sbad) break;
    }
  } else {
    // =========================== decoder group ===============================
    const int d = b - ENC_BLK;
    const int r = (g << 10) + (d << 3) + j;  // owned gate row
    float4 w1[16], wr[16];
#pragma unroll
    for (int k = 0; k < 16; k++) {
      const int m = (k + s16) & 15;
      w1[k] = *(const float4*)&Wihd[(size_t)r * 2048 + s16 * 64 + m * 4];
      const float4 a = *(const float4*)&Wihd[(size_t)r * 2048 + 1024 + s16 * 64 + m * 4];
      const float4 c = *(const float4*)&Whhd[(size_t)r * 1024 + s16 * 64 + m * 4];
      wr[k] = make_float4(a.x + c.x, a.y + c.y, a.z + c.z, a.w + c.w);
    }
    if (tid < 32) {
      const int gg2 = tid >> 3, jj2 = tid & 7;
      bd[tid] = bihd[(gg2 << 10) + (d << 3) + jj2] + bhhd[(gg2 << 10) + (d << 3) + jj2];
    }
    aw[tid] = 0.f;
    if (tid < 256) {
      xbuf[tid] = make_float4(0.f, 0.f, 0.f, 0.f);
      dbuf[tid] = make_float4(0.f, 0.f, 0.f, 0.f);
    }
    float dc = 0.f;  // cell state (tid<8)
    float4 wo = make_float4(0.f, 0.f, 0.f, 0.f);
    if (tid < 256) wo = *(const float4*)&Wout[tid * 4];
    const float boutv = bout[0];
    __syncthreads();
    const bool relay = (s_slot == 0);  // dh-relay for this XCD

    bool failed = false;
    for (int t = 0; t < T_STEPS; t++) {
      // --- pre-dh: softmax partials over stale aw (1 slot/thread) ---
      const float battn_t = battn[t];
      const float ex0 = expf(aw[tid]);  // aw in [0,1]: exp safe, no max needed
      float so = (tid == t) ? 0.f : ex0;
#pragma unroll
      for (int mk = 1; mk <= 32; mk <<= 1) so += __shfl_xor(so, mk, 64);
      if (lane == 0) red[w] = so;

      // --- consume eh(t) (relay forwards at encoder pace; usually instant) ---
      float4 wae = make_float4(0.f, 0.f, 0.f, 0.f);
      float4 wad = make_float4(0.f, 0.f, 0.f, 0.f);
      float epe = 0.f;
      int ok1 = 1;
      if (tid < 256) {
        wae = *(const float4*)&Wattn[(size_t)t * 2048 + tid * 4];
        wad = *(const float4*)&Wattn[(size_t)t * 2048 + 1024 + tid * 4];
        const fv4 ev = poll_any(&myeloc[(size_t)t * 1024 + tid * 4],
                                &ehbuf[(size_t)t * 1024 + tid * 4], &sfallE, &ok1);
        epe = wae.x * ev.x + wae.y * ev.y + wae.z * ev.z + wae.w * ev.w;
        xbuf[tid] = make_float4(ev.x, ev.y, ev.z, ev.w);
      }
      if (!ok1) sbad = 1;
#pragma unroll
      for (int mk = 1; mk <= 32; mk <<= 1) epe += __shfl_xor(epe, mk, 64);
      if (lane == 0 && w < 4) redE[w] = epe;
      __syncthreads();  // B1
      if (sbad) { failed = true; break; }

      // --- g1 = Wihd[:,:H] @ eh(t) (dh-independent) ---
      float g1 = 0.f;
#pragma unroll
      for (int k = 0; k < 16; k++) {
        const int m = (k + s16) & 15;
        const float4 x = xbuf[s16 * 16 + m];
        g1 += w1[k].x * x.x + w1[k].y * x.y + w1[k].z * x.z + w1[k].w * x.w;
      }
      g1 += __shfl_xor(g1, 4, 64);
      g1 += __shfl_xor(g1, 8, 64);
      g1 += __shfl_xor(g1, 16, 64);
      g1 += __shfl_xor(g1, 32, 64);
      if (lane < 4) GA[w * 4 + lane] = g1;

      // --- poll dh(t-1): the recurrence-critical handoff ---
      float epd = 0.f;
      int ok2 = 1;
      if (t > 0 && tid < 256) {
        const float* pllc = &dhbuf[(size_t)(t - 1) * 1024 + tid * 4];
        fv4 dv;
        if (relay && use_loc) {
          dv = poll2_llc(pllc, POLL_LIMIT, &ok2);
          st_loc16(&mydloc[(size_t)(t - 1) * 1024 + tid * 4], dv);
        } else {
          dv = poll_any(&mydloc[(size_t)(t - 1) * 1024 + tid * 4], pllc, &sfallD, &ok2);
        }
        epd = wad.x * dv.x + wad.y * dv.y + wad.z * dv.z + wad.w * dv.w;
        dbuf[tid] = make_float4(dv.x, dv.y, dv.z, dv.w);
      }
      if (!ok2) sbad = 1;
#pragma unroll
      for (int mk = 1; mk <= 32; mk <<= 1) epd += __shfl_xor(epd, mk, 64);
      if (lane == 0 && w < 4) redE2[w] = epd;
      __syncthreads();  // B2
      if (sbad) { failed = true; break; }

      // --- g2 = (Wihd[:,H:]+Whhd) @ dh(t-1) ---
      float g2 = 0.f;
#pragma unroll
      for (int k = 0; k < 16; k++) {
        const int m = (k + s16) & 15;
        const float4 dd = dbuf[s16 * 16 + m];
        g2 += wr[k].x * dd.x + wr[k].y * dd.y + wr[k].z * dd.z + wr[k].w * dd.w;
      }
      g2 += __shfl_xor(g2, 4, 64);
      g2 += __shfl_xor(g2, 8, 64);
      g2 += __shfl_xor(g2, 16, 64);
      g2 += __shfl_xor(g2, 32, 64);
      if (lane < 4) GB[w * 4 + lane] = g2;

      // --- softmax finish (all threads redundantly) + aw update ---
      const float e_t = redE[0] + redE[1] + redE[2] + redE[3] +
                        redE2[0] + redE2[1] + redE2[2] + redE2[3] + battn_t;
      const float exden = expf(e_t);
      const float inv = 1.f / (red[0] + red[1] + red[2] + red[3] +
                               red[4] + red[5] + red[6] + red[7] + exden);
      const float awt = exden * inv;
      aw[tid] = ((tid == t) ? exden : ex0) * inv;
      __syncthreads();  // S3 (GA/GB ready)

      // --- decoder cell (tid<8) + coalesced publication ---
      if (tid < 8) {
        const float gi = awt * GA[tid]      + GB[tid]      + bd[tid];
        const float gf = awt * GA[8 + tid]  + GB[8 + tid]  + bd[8 + tid];
        const float gg = awt * GA[16 + tid] + GB[16 + tid] + bd[16 + tid];
        const float go = awt * GA[24 + tid] + GB[24 + tid] + bd[24 + tid];
        const float c = sigf(gf) * dc + sigf(gi) * tanhf(gg);
        dc = c;
        const float h = sigf(go) * tanhf(c);
        st_llc4(&dhbuf[(size_t)t * 1024 + (d << 3) + tid], h);
        if (use_loc) st_loc4(&mydloc[(size_t)t * 1024 + (d << 3) + tid], h);
      }
    }

    // --- epilogue: out[t] = W_out·dh(t) + b_out, 4 t-values per block ---
    if (!failed) {
#pragma unroll
      for (int i = 0; i < 4; i++) {
        const int t = d * 4 + i;
        float op = 0.f;
        int ok = 1;
        if (tid < 256) {
          const fv4 dv = poll2_llc(&dhbuf[(size_t)t * 1024 + tid * 4], POLL_LIMIT, &ok);
          op = wo.x * dv.x + wo.y * dv.y + wo.z * dv.z + wo.w * dv.w;
        }
        if (!ok) break;
#pragma unroll
        for (int mk = 1; mk <= 32; mk <<= 1) op += __shfl_xor(op, mk, 64);
        if (lane == 0 && w < 4) red2[w] = op;
        __syncthreads();
        if (tid == 0) out[t] = red2[0] + red2[1] + red2[2] + red2[3] + boutv;
        __syncthreads();
      }
    }
  }
}

// ---------------------------------- launch ------------------------------------
extern "C" void kernel_launch(void* const* d_in, const int* in_sizes, int n_in,
                              void* d_out, int out_size, void* d_ws, size_t ws_size,
                              hipStream_t stream) {
  const float* X     = (const float*)d_in[0];
  const float* Wihe  = (const float*)d_in[2];
  const float* Whhe  = (const float*)d_in[3];
  const float* bihe  = (const float*)d_in[4];
  const float* bhhe  = (const float*)d_in[5];
  const float* Wattn = (const float*)d_in[6];
  const float* battn = (const float*)d_in[7];
  const float* Wihd  = (const float*)d_in[8];
  const float* Whhd  = (const float*)d_in[9];
  const float* bihd  = (const float*)d_in[10];
  const float* bhhd  = (const float*)d_in[11];
  const float* Wo    = (const float*)d_in[12];
  const float* bo    = (const float*)d_in[13];
  float* out = (float*)d_out;

  float* ws    = (float*)d_ws;
  float* px    = ws;                                  // 512*1024*4 floats (8 MB)
  float* ehbuf = px + (size_t)T_STEPS * 1024 * 4;     // 2 MB
  float* dhbuf = ehbuf + REPSZ;                       // 2 MB
  int*   ctrs  = (int*)(dhbuf + REPSZ);               // 16 ints (enc[8], dec[8])
  float* ehloc = (float*)(ctrs + 16);                 // 8 x 2 MB XCD-local
  float* dhloc = ehloc + 8 * REPSZ;                   // 8 x 2 MB XCD-local

  const size_t need_min  = ((size_t)T_STEPS * 1024 * 6) * sizeof(float) + 16 * sizeof(int);
  const size_t need_full = need_min + 16 * REPSZ * sizeof(float);
  if (ws_size < need_min) return;
  const int use_loc = (ws_size >= need_full) ? 1 : 0;

  prep_gemm<<<dim3(64, 8), 256, 0, stream>>>(X, Wihe, bihe, bhhe, px, ctrs);
  lstm_persist<<<NBLK, NTHR, 0, stream>>>(
      Whhe, Wattn, battn, Wihd, Whhd, bihd, bhhd, Wo, bo, px, ehbuf, dhbuf,
      ehloc, dhloc, ctrs, use_loc, out);
}

// Round 10
// 2045.124 us; speedup vs baseline: 1.0990x; 1.0990x over previous
//
#include <hip/hip_runtime.h>
#include <math.h>

// TransformersLSTM: T=512, I=512, H=1024, L=512, O=1.
// Split-grid persistent kernel: blocks 0..127 encoder, 128..255 decoder.
// Weights VGPR-resident. Tagless handoff on 0xAA-poisoned write-once buffers
// (consumers spin on data granules, dword != 0xAAAAAAAA).
// R10 = R8 (best: 1999us) + FULL-CACHE-LINE publication: each block's 8 h
// values live in their own 128B line ([t][block][32f], 8 real + 24 pad); the
// publishing wave stores from 32 lanes (pad lanes write 0) -> one coalesced
// full-line sc0 sc1 write. Tests the partial-line/write-combine visibility
// theory: R8's 32B fragment stores can linger in WC buffers / force LLC
// partial-line merges, plausibly the ~2.5us unexplained handoff term.
// (R9's XCD relay reverted: WRITE_SIZE proved it active, yet it regressed —
// congestion falsified. R6 replication and R8 sampling also falsified.)

#define T_STEPS 512
#define ENC_BLK 128
#define NBLK    256
#define NTHR    512
#define POLL_LIMIT 30000u

typedef float fv4 __attribute__((ext_vector_type(4)));

__device__ __forceinline__ float sigf(float x) { return 1.0f / (1.0f + expf(-x)); }

// 4B cache-bypass store (to LLC); issued by one wave, fully coalesced.
__device__ __forceinline__ void st_bypass4(float* p, float v) {
  asm volatile("global_store_dword %0, %1, off sc0 sc1"
               :: "v"(p), "v"(v) : "memory");
}

__device__ __forceinline__ bool valid4(fv4 v) {
  return __float_as_uint(v.x) != 0xAAAAAAAAu && __float_as_uint(v.y) != 0xAAAAAAAAu &&
         __float_as_uint(v.z) != 0xAAAAAAAAu && __float_as_uint(v.w) != 0xAAAAAAAAu;
}

// 2-deep pipelined poison-poll of one 16B granule (sliding vmcnt(1) window).
__device__ __forceinline__ fv4 poll2(const float* p, int* okp) {
  fv4 a, b;
  int ok = 1;
  asm volatile("global_load_dwordx4 %0, %1, off sc0 sc1" : "=v"(a) : "v"(p) : "memory");
  for (unsigned it = 0;; ++it) {
    asm volatile("global_load_dwordx4 %0, %1, off sc0 sc1" : "=v"(b) : "v"(p) : "memory");
    asm volatile("s_waitcnt vmcnt(1)" : "+v"(a) :: "memory");  // oldest (a) done
    if (valid4(a)) { asm volatile("s_waitcnt vmcnt(0)" ::: "memory"); break; }
    asm volatile("global_load_dwordx4 %0, %1, off sc0 sc1" : "=v"(a) : "v"(p) : "memory");
    asm volatile("s_waitcnt vmcnt(1)" : "+v"(b) :: "memory");  // oldest (b) done
    if (valid4(b)) { asm volatile("s_waitcnt vmcnt(0)" ::: "memory"); a = b; break; }
    if (it > POLL_LIMIT) { ok = 0; asm volatile("s_waitcnt vmcnt(0)" ::: "memory"); break; }
  }
  *okp = ok;
  return a;
}

// ------------- precompute PX = W_ih_e @ x_t + b_ih_e + b_hh_e -----------------
// px[(t*1024 + h)*4 + g] for gate row r = g*1024 + h.
__global__ __launch_bounds__(256) void prep_gemm(const float* __restrict__ X,
                                                 const float* __restrict__ Wih,
                                                 const float* __restrict__ bih,
                                                 const float* __restrict__ bhh,
                                                 float* __restrict__ px) {
  __shared__ float Ws[64][68];
  __shared__ float Xs[64][68];
  const int r0 = blockIdx.x * 64;
  const int t0 = blockIdx.y * 64;
  const int tid = threadIdx.x;
  const int tr = tid & 15;
  const int tc = tid >> 4;
  float acc[4][4] = {{0.f}};
  for (int k0 = 0; k0 < 512; k0 += 64) {
    __syncthreads();
    const int lr = tid >> 4;
    const int lc = (tid & 15) * 4;
#pragma unroll
    for (int rep = 0; rep < 4; rep++) {
      const int row = lr + rep * 16;
      const float4 wv = *(const float4*)&Wih[(size_t)(r0 + row) * 512 + k0 + lc];
      Ws[lc + 0][row] = wv.x; Ws[lc + 1][row] = wv.y;
      Ws[lc + 2][row] = wv.z; Ws[lc + 3][row] = wv.w;
      const float4 xv = *(const float4*)&X[(size_t)(t0 + row) * 512 + k0 + lc];
      Xs[row][lc + 0] = xv.x; Xs[row][lc + 1] = xv.y;
      Xs[row][lc + 2] = xv.z; Xs[row][lc + 3] = xv.w;
    }
    __syncthreads();
    for (int kk = 0; kk < 64; kk++) {
      float a[4], x[4];
#pragma unroll
      for (int i = 0; i < 4; i++) a[i] = Ws[kk][tr * 4 + i];
#pragma unroll
      for (int j = 0; j < 4; j++) x[j] = Xs[tc * 4 + j][kk];
#pragma unroll
      for (int i = 0; i < 4; i++)
#pragma unroll
        for (int j = 0; j < 4; j++) acc[i][j] += a[i] * x[j];
    }
  }
#pragma unroll
  for (int i = 0; i < 4; i++) {
    const int r = r0 + tr * 4 + i;
    const int g = r >> 10, h = r & 1023;
    const float bsum = bih[r] + bhh[r];
#pragma unroll
    for (int j = 0; j < 4; j++) {
      const int t = t0 + tc * 4 + j;
      px[((size_t)t * 1024 + h) * 4 + g] = acc[i][j] + bsum;
    }
  }
}

// ------------------------------ persistent kernel -----------------------------
// 512 threads: wave w (0..7) owns gate g=w>>1, h-rows j=(w&1)*4+ri (ri=lane&3);
// lane s16=lane>>2 covers K in [s16*64, s16*64+64) as 16 float4 (rot by s16).
// Handoff layout: [t][block][lst floats] (lst=32 padded-line, or 8 compact);
// consumer thread tid's granule = lst*(tid>>1) + 4*(tid&1) == h[4*tid..4*tid+3].
__global__ __launch_bounds__(512, 1) void lstm_persist(
    const float* __restrict__ Whhe, const float* __restrict__ Wattn,
    const float* __restrict__ battn, const float* __restrict__ Wihd,
    const float* __restrict__ Whhd, const float* __restrict__ bihd,
    const float* __restrict__ bhhd, const float* __restrict__ Wout,
    const float* __restrict__ bout, const float* __restrict__ px,
    float* ehbuf, float* dhbuf, int lst, float* out) {
  __shared__ float4 xbuf[256];   // eh copy (both groups)
  __shared__ float4 dbuf[256];   // dh copy (decoder)
  __shared__ float  aw[512];     // softmax state (decoder)
  __shared__ float  GA[32];      // gate sums (enc ge / dec g1)
  __shared__ float  GB[32];      // dec g2
  __shared__ float  bd[32];      // decoder bias
  __shared__ float  redE[4];     // energy (eh part)
  __shared__ float  redE2[4];    // energy (dh part)
  __shared__ float  red[8];      // softmax sums (8 waves)
  __shared__ float  red2[4];     // out-dot reduce
  __shared__ int    sbad;

  const int b    = blockIdx.x;
  const int tid  = threadIdx.x;
  const int w    = tid >> 6;
  const int lane = tid & 63;
  const int ri   = lane & 3;    // row-in-wave
  const int s16  = lane >> 2;   // K-segment 0..15 (64 floats)
  const int g    = w >> 1;      // gate index
  const int j    = ((w & 1) << 2) + ri;  // h-row within block's 8
  const size_t tstr = (size_t)128 * lst;               // floats per timestep
  const size_t goff = (size_t)(tid >> 1) * lst + ((tid & 1) << 2);  // consumer granule

  if (b < ENC_BLK) {
    // =========================== encoder group ===============================
    const int e = b;
    const int r = (g << 10) + (e << 3) + j;  // owned gate row
    float4 we[16];
#pragma unroll
    for (int k = 0; k < 16; k++) {
      const int m = (k + s16) & 15;
      we[k] = *(const float4*)&Whhe[(size_t)r * 1024 + s16 * 64 + m * 4];
    }
    if (tid < 256) xbuf[tid] = make_float4(0.f, 0.f, 0.f, 0.f);
    if (tid == 0) sbad = 0;
    float ec = 0.f;  // cell state (tid<8)
    __syncthreads();

    for (int t = 0; t < T_STEPS; t++) {
      float ge = 0.f;
#pragma unroll
      for (int k = 0; k < 16; k++) {
        const int m = (k + s16) & 15;
        const float4 x = xbuf[s16 * 16 + m];
        ge += we[k].x * x.x + we[k].y * x.y + we[k].z * x.z + we[k].w * x.w;
      }
      if (s16 == 0) ge += px[((size_t)t * 1024 + (e << 3) + j) * 4 + g];
      ge += __shfl_xor(ge, 4, 64);
      ge += __shfl_xor(ge, 8, 64);
      ge += __shfl_xor(ge, 16, 64);
      ge += __shfl_xor(ge, 32, 64);
      if (lane < 4) GA[w * 4 + lane] = ge;  // GA[g*8+j]
      __syncthreads();  // S1
      float h = 0.f;    // pad lanes publish 0 (non-poison)
      if (tid < 8) {
        const float gi = GA[tid], gf = GA[8 + tid], gg = GA[16 + tid], go = GA[24 + tid];
        const float c = sigf(gf) * ec + sigf(gi) * tanhf(gg);
        ec = c;
        h = sigf(go) * tanhf(c);
      }
      if (tid < lst)  // one coalesced full-line (128B when lst=32) publication
        st_bypass4(&ehbuf[(size_t)t * tstr + (size_t)e * lst + tid], h);
      int ok = 1;
      if (tid < 256) {
        const fv4 ev = poll2(&ehbuf[(size_t)t * tstr + goff], &ok);
        xbuf[tid] = make_float4(ev.x, ev.y, ev.z, ev.w);
      }
      if (!ok) sbad = 1;
      __syncthreads();  // S2
      if (sbad) break;
    }
  } else {
    // =========================== decoder group ===============================
    const int d = b - ENC_BLK;
    const int r = (g << 10) + (d << 3) + j;  // owned gate row
    float4 w1[16], wr[16];
#pragma unroll
    for (int k = 0; k < 16; k++) {
      const int m = (k + s16) & 15;
      w1[k] = *(const float4*)&Wihd[(size_t)r * 2048 + s16 * 64 + m * 4];
      const float4 a = *(const float4*)&Wihd[(size_t)r * 2048 + 1024 + s16 * 64 + m * 4];
      const float4 c = *(const float4*)&Whhd[(size_t)r * 1024 + s16 * 64 + m * 4];
      wr[k] = make_float4(a.x + c.x, a.y + c.y, a.z + c.z, a.w + c.w);
    }
    if (tid < 32) {
      const int gg2 = tid >> 3, jj2 = tid & 7;
      bd[tid] = bihd[(gg2 << 10) + (d << 3) + jj2] + bhhd[(gg2 << 10) + (d << 3) + jj2];
    }
    aw[tid] = 0.f;
    if (tid < 256) {
      xbuf[tid] = make_float4(0.f, 0.f, 0.f, 0.f);
      dbuf[tid] = make_float4(0.f, 0.f, 0.f, 0.f);
    }
    if (tid == 0) sbad = 0;
    float dc = 0.f;  // cell state (tid<8)
    float4 wo = make_float4(0.f, 0.f, 0.f, 0.f);
    if (tid < 256) wo = *(const float4*)&Wout[tid * 4];
    const float boutv = bout[0];
    __syncthreads();

    bool failed = false;
    for (int t = 0; t < T_STEPS; t++) {
      // --- pre-dh: softmax partials over stale aw (1 slot/thread) ---
      const float battn_t = battn[t];
      const float ex0 = expf(aw[tid]);  // aw in [0,1]: exp safe, no max needed
      float so = (tid == t) ? 0.f : ex0;
#pragma unroll
      for (int mk = 1; mk <= 32; mk <<= 1) so += __shfl_xor(so, mk, 64);
      if (lane == 0) red[w] = so;

      // --- poll eh(t) (encoder runs ahead) + eh energy dot ---
      float4 wae = make_float4(0.f, 0.f, 0.f, 0.f);
      float4 wad = make_float4(0.f, 0.f, 0.f, 0.f);
      float epe = 0.f;
      int ok1 = 1;
      if (tid < 256) {
        wae = *(const float4*)&Wattn[(size_t)t * 2048 + tid * 4];
        wad = *(const float4*)&Wattn[(size_t)t * 2048 + 1024 + tid * 4];
        const fv4 ev = poll2(&ehbuf[(size_t)t * tstr + goff], &ok1);
        epe = wae.x * ev.x + wae.y * ev.y + wae.z * ev.z + wae.w * ev.w;
        xbuf[tid] = make_float4(ev.x, ev.y, ev.z, ev.w);
      }
      if (!ok1) sbad = 1;
#pragma unroll
      for (int mk = 1; mk <= 32; mk <<= 1) epe += __shfl_xor(epe, mk, 64);
      if (lane == 0 && w < 4) redE[w] = epe;
      __syncthreads();  // B1
      if (sbad) { failed = true; break; }

      // --- g1 = Wihd[:,:H] @ eh(t) (dh-independent) ---
      float g1 = 0.f;
#pragma unroll
      for (int k = 0; k < 16; k++) {
        const int m = (k + s16) & 15;
        const float4 x = xbuf[s16 * 16 + m];
        g1 += w1[k].x * x.x + w1[k].y * x.y + w1[k].z * x.z + w1[k].w * x.w;
      }
      g1 += __shfl_xor(g1, 4, 64);
      g1 += __shfl_xor(g1, 8, 64);
      g1 += __shfl_xor(g1, 16, 64);
      g1 += __shfl_xor(g1, 32, 64);
      if (lane < 4) GA[w * 4 + lane] = g1;

      // --- poll dh(t-1): the recurrence-critical handoff ---
      float epd = 0.f;
      int ok2 = 1;
      if (t > 0 && tid < 256) {
        const fv4 dv = poll2(&dhbuf[(size_t)(t - 1) * tstr + goff], &ok2);
        epd = wad.x * dv.x + wad.y * dv.y + wad.z * dv.z + wad.w * dv.w;
        dbuf[tid] = make_float4(dv.x, dv.y, dv.z, dv.w);
      }
      if (!ok2) sbad = 1;
#pragma unroll
      for (int mk = 1; mk <= 32; mk <<= 1) epd += __shfl_xor(epd, mk, 64);
      if (lane == 0 && w < 4) redE2[w] = epd;
      __syncthreads();  // B2
      if (sbad) { failed = true; break; }

      // --- g2 = (Wihd[:,H:]+Whhd) @ dh(t-1) ---
      float g2 = 0.f;
#pragma unroll
      for (int k = 0; k < 16; k++) {
        const int m = (k + s16) & 15;
        const float4 dd = dbuf[s16 * 16 + m];
        g2 += wr[k].x * dd.x + wr[k].y * dd.y + wr[k].z * dd.z + wr[k].w * dd.w;
      }
      g2 += __shfl_xor(g2, 4, 64);
      g2 += __shfl_xor(g2, 8, 64);
      g2 += __shfl_xor(g2, 16, 64);
      g2 += __shfl_xor(g2, 32, 64);
      if (lane < 4) GB[w * 4 + lane] = g2;

      // --- softmax finish (all threads redundantly) + aw update ---
      const float e_t = redE[0] + redE[1] + redE[2] + redE[3] +
                        redE2[0] + redE2[1] + redE2[2] + redE2[3] + battn_t;
      const float exden = expf(e_t);
      const float inv = 1.f / (red[0] + red[1] + red[2] + red[3] +
                               red[4] + red[5] + red[6] + red[7] + exden);
      const float awt = exden * inv;
      aw[tid] = ((tid == t) ? exden : ex0) * inv;
      __syncthreads();  // S3 (GA/GB ready)

      // --- decoder cell (tid<8) + coalesced full-line publication ---
      float h = 0.f;
      if (tid < 8) {
        const float gi = awt * GA[tid]      + GB[tid]      + bd[tid];
        const float gf = awt * GA[8 + tid]  + GB[8 + tid]  + bd[8 + tid];
        const float gg = awt * GA[16 + tid] + GB[16 + tid] + bd[16 + tid];
        const float go = awt * GA[24 + tid] + GB[24 + tid] + bd[24 + tid];
        const float c = sigf(gf) * dc + sigf(gi) * tanhf(gg);
        dc = c;
        h = sigf(go) * tanhf(c);
      }
      if (tid < lst)
        st_bypass4(&dhbuf[(size_t)t * tstr + (size_t)d * lst + tid], h);
    }

    // --- epilogue: out[t] = W_out·dh(t) + b_out, 4 t-values per block ---
    if (!failed) {
#pragma unroll
      for (int i = 0; i < 4; i++) {
        const int t = d * 4 + i;
        float op = 0.f;
        int ok = 1;
        if (tid < 256) {
          const fv4 dv = poll2(&dhbuf[(size_t)t * tstr + goff], &ok);
          op = wo.x * dv.x + wo.y * dv.y + wo.z * dv.z + wo.w * dv.w;
        }
        if (!ok) break;
#pragma unroll
        for (int mk = 1; mk <= 32; mk <<= 1) op += __shfl_xor(op, mk, 64);
        if (lane == 0 && w < 4) red2[w] = op;
        __syncthreads();
        if (tid == 0) out[t] = red2[0] + red2[1] + red2[2] + red2[3] + boutv;
        __syncthreads();
      }
    }
  }
}

// ---------------------------------- launch ------------------------------------
extern "C" void kernel_launch(void* const* d_in, const int* in_sizes, int n_in,
                              void* d_out, int out_size, void* d_ws, size_t ws_size,
                              hipStream_t stream) {
  const float* X     = (const float*)d_in[0];
  const float* Wihe  = (const float*)d_in[2];
  const float* Whhe  = (const float*)d_in[3];
  const float* bihe  = (const float*)d_in[4];
  const float* bhhe  = (const float*)d_in[5];
  const float* Wattn = (const float*)d_in[6];
  const float* battn = (const float*)d_in[7];
  const float* Wihd  = (const float*)d_in[8];
  const float* Whhd  = (const float*)d_in[9];
  const float* bihd  = (const float*)d_in[10];
  const float* bhhd  = (const float*)d_in[11];
  const float* Wo    = (const float*)d_in[12];
  const float* bo    = (const float*)d_in[13];
  float* out = (float*)d_out;

  const size_t px_elems = (size_t)T_STEPS * 1024 * 4;  // 8 MB
  // padded full-line layout: 128 blocks x 32 floats (128B) per step per buffer
  const size_t buf_pad = (size_t)T_STEPS * 128 * 32;   // 8 MB each
  const size_t buf_cmp = (size_t)T_STEPS * 1024;       // 2 MB each (R8 compact)
  const size_t need_pad = (px_elems + 2 * buf_pad) * sizeof(float);
  const size_t need_cmp = (px_elems + 2 * buf_cmp) * sizeof(float);
  int lst;
  size_t bsz;
  if (ws_size >= need_pad)      { lst = 32; bsz = buf_pad; }
  else if (ws_size >= need_cmp) { lst = 8;  bsz = buf_cmp; }
  else return;

  float* ws    = (float*)d_ws;
  float* px    = ws;
  float* ehbuf = px + px_elems;
  float* dhbuf = ehbuf + bsz;

  prep_gemm<<<dim3(64, 8), 256, 0, stream>>>(X, Wihe, bihe, bhhe, px);
  lstm_persist<<<NBLK, NTHR, 0, stream>>>(
      Whhe, Wattn, battn, Wihd, Whhd, bihd, bhhd, Wo, bo, px, ehbuf, dhbuf,
      lst, out);
}

// Round 12
// 1816.223 us; speedup vs baseline: 1.2375x; 1.1260x over previous
//
#include <hip/hip_runtime.h>
#include <math.h>

// TransformersLSTM: T=512, I=512, H=1024, L=512, O=1.
// Split-grid persistent kernel: blocks 0..127 encoder, 128..255 decoder.
// Weights VGPR-resident. Tagless handoff on 0xAA-poisoned write-once buffers
// (consumers spin on data granules, dword != 0xAAAAAAAA).
// R12 = R8 (best sound structure: 1999us) + COMPILER-MANAGED split-transaction
// polls. R11's hand-rolled in-flight asm registers were unsound (compiler may
// copy a pending VGPR at the loop back edge -> accepted garbage, absmax 1.5e-5).
// Here the speculative samples are plain C++ relaxed agent atomic loads: the
// backend issues them at source position and inserts s_waitcnt before first
// use (never copying a pending register). eh(t) samples issued at end of
// iteration t-1 (loop-carried floats); dh(t-1) samples issued after B1 and
// consumed after the g1 matvec (RTT covered). Poison -> poll2 fallback.

#define T_STEPS 512
#define ENC_BLK 128
#define NBLK    256
#define NTHR    512
#define POLL_LIMIT 30000u

typedef float fv4 __attribute__((ext_vector_type(4)));

__device__ __forceinline__ float sigf(float x) { return 1.0f / (1.0f + expf(-x)); }

// relaxed agent-scope load: device-coherent dword load, compiler-scheduled.
__device__ __forceinline__ float ld_f(const float* p) {
  return __hip_atomic_load(p, __ATOMIC_RELAXED, __HIP_MEMORY_SCOPE_AGENT);
}

// 4B cache-bypass store (to LLC); issued by one wave, fully coalesced.
__device__ __forceinline__ void st_bypass4(float* p, float v) {
  asm volatile("global_store_dword %0, %1, off sc0 sc1"
               :: "v"(p), "v"(v) : "memory");
}

__device__ __forceinline__ bool valid4(fv4 v) {
  return __float_as_uint(v.x) != 0xAAAAAAAAu && __float_as_uint(v.y) != 0xAAAAAAAAu &&
         __float_as_uint(v.z) != 0xAAAAAAAAu && __float_as_uint(v.w) != 0xAAAAAAAAu;
}
__device__ __forceinline__ bool validf(float a, float b, float c, float d) {
  return __float_as_uint(a) != 0xAAAAAAAAu && __float_as_uint(b) != 0xAAAAAAAAu &&
         __float_as_uint(c) != 0xAAAAAAAAu && __float_as_uint(d) != 0xAAAAAAAAu;
}

// 2-deep pipelined poison-poll of one 16B granule (sliding vmcnt(1) window).
// Self-contained asm (all waits internal) — sound.
__device__ __forceinline__ fv4 poll2(const float* p, int* okp) {
  fv4 a, b;
  int ok = 1;
  asm volatile("global_load_dwordx4 %0, %1, off sc0 sc1" : "=v"(a) : "v"(p) : "memory");
  for (unsigned it = 0;; ++it) {
    asm volatile("global_load_dwordx4 %0, %1, off sc0 sc1" : "=v"(b) : "v"(p) : "memory");
    asm volatile("s_waitcnt vmcnt(1)" : "+v"(a) :: "memory");  // oldest (a) done
    if (valid4(a)) { asm volatile("s_waitcnt vmcnt(0)" ::: "memory"); break; }
    asm volatile("global_load_dwordx4 %0, %1, off sc0 sc1" : "=v"(a) : "v"(p) : "memory");
    asm volatile("s_waitcnt vmcnt(1)" : "+v"(b) :: "memory");  // oldest (b) done
    if (valid4(b)) { asm volatile("s_waitcnt vmcnt(0)" ::: "memory"); a = b; break; }
    if (it > POLL_LIMIT) { ok = 0; asm volatile("s_waitcnt vmcnt(0)" ::: "memory"); break; }
  }
  *okp = ok;
  return a;
}

// ------------- precompute PX = W_ih_e @ x_t + b_ih_e + b_hh_e -----------------
// px[(t*1024 + h)*4 + g] for gate row r = g*1024 + h.
__global__ __launch_bounds__(256) void prep_gemm(const float* __restrict__ X,
                                                 const float* __restrict__ Wih,
                                                 const float* __restrict__ bih,
                                                 const float* __restrict__ bhh,
                                                 float* __restrict__ px) {
  __shared__ float Ws[64][68];
  __shared__ float Xs[64][68];
  const int r0 = blockIdx.x * 64;
  const int t0 = blockIdx.y * 64;
  const int tid = threadIdx.x;
  const int tr = tid & 15;
  const int tc = tid >> 4;
  float acc[4][4] = {{0.f}};
  for (int k0 = 0; k0 < 512; k0 += 64) {
    __syncthreads();
    const int lr = tid >> 4;
    const int lc = (tid & 15) * 4;
#pragma unroll
    for (int rep = 0; rep < 4; rep++) {
      const int row = lr + rep * 16;
      const float4 wv = *(const float4*)&Wih[(size_t)(r0 + row) * 512 + k0 + lc];
      Ws[lc + 0][row] = wv.x; Ws[lc + 1][row] = wv.y;
      Ws[lc + 2][row] = wv.z; Ws[lc + 3][row] = wv.w;
      const float4 xv = *(const float4*)&X[(size_t)(t0 + row) * 512 + k0 + lc];
      Xs[row][lc + 0] = xv.x; Xs[row][lc + 1] = xv.y;
      Xs[row][lc + 2] = xv.z; Xs[row][lc + 3] = xv.w;
    }
    __syncthreads();
    for (int kk = 0; kk < 64; kk++) {
      float a[4], x[4];
#pragma unroll
      for (int i = 0; i < 4; i++) a[i] = Ws[kk][tr * 4 + i];
#pragma unroll
      for (int j = 0; j < 4; j++) x[j] = Xs[tc * 4 + j][kk];
#pragma unroll
      for (int i = 0; i < 4; i++)
#pragma unroll
        for (int j = 0; j < 4; j++) acc[i][j] += a[i] * x[j];
    }
  }
#pragma unroll
  for (int i = 0; i < 4; i++) {
    const int r = r0 + tr * 4 + i;
    const int g = r >> 10, h = r & 1023;
    const float bsum = bih[r] + bhh[r];
#pragma unroll
    for (int j = 0; j < 4; j++) {
      const int t = t0 + tc * 4 + j;
      px[((size_t)t * 1024 + h) * 4 + g] = acc[i][j] + bsum;
    }
  }
}

// ------------------------------ persistent kernel -----------------------------
// 512 threads: wave w (0..7) owns gate g=w>>1, h-rows j=(w&1)*4+ri (ri=lane&3);
// lane s16=lane>>2 covers K in [s16*64, s16*64+64) as 16 float4 (rot by s16).
__global__ __launch_bounds__(512, 1) void lstm_persist(
    const float* __restrict__ Whhe, const float* __restrict__ Wattn,
    const float* __restrict__ battn, const float* __restrict__ Wihd,
    const float* __restrict__ Whhd, const float* __restrict__ bihd,
    const float* __restrict__ bhhd, const float* __restrict__ Wout,
    const float* __restrict__ bout, const float* __restrict__ px,
    float* ehbuf, float* dhbuf, float* out) {
  __shared__ float4 xbuf[256];   // eh copy (both groups)
  __shared__ float4 dbuf[256];   // dh copy (decoder)
  __shared__ float  aw[512];     // softmax state (decoder)
  __shared__ float  GA[32];      // gate sums (enc ge / dec g1)
  __shared__ float  GB[32];      // dec g2
  __shared__ float  bd[32];      // decoder bias
  __shared__ float  redE[4];     // energy (eh part)
  __shared__ float  redE2[4];    // energy (dh part)
  __shared__ float  red[8];      // softmax sums (8 waves)
  __shared__ float  red2[4];     // out-dot reduce
  __shared__ int    sbad;

  const int b    = blockIdx.x;
  const int tid  = threadIdx.x;
  const int w    = tid >> 6;
  const int lane = tid & 63;
  const int ri   = lane & 3;    // row-in-wave
  const int s16  = lane >> 2;   // K-segment 0..15 (64 floats)
  const int g    = w >> 1;      // gate index
  const int j    = ((w & 1) << 2) + ri;  // h-row within block's 8

  if (b < ENC_BLK) {
    // =========================== encoder group (exact R8) ====================
    const int e = b;
    const int r = (g << 10) + (e << 3) + j;  // owned gate row
    float4 we[16];
#pragma unroll
    for (int k = 0; k < 16; k++) {
      const int m = (k + s16) & 15;
      we[k] = *(const float4*)&Whhe[(size_t)r * 1024 + s16 * 64 + m * 4];
    }
    if (tid < 256) xbuf[tid] = make_float4(0.f, 0.f, 0.f, 0.f);
    if (tid == 0) sbad = 0;
    float ec = 0.f;  // cell state (tid<8)
    __syncthreads();

    for (int t = 0; t < T_STEPS; t++) {
      float ge = 0.f;
#pragma unroll
      for (int k = 0; k < 16; k++) {
        const int m = (k + s16) & 15;
        const float4 x = xbuf[s16 * 16 + m];
        ge += we[k].x * x.x + we[k].y * x.y + we[k].z * x.z + we[k].w * x.w;
      }
      if (s16 == 0) ge += px[((size_t)t * 1024 + (e << 3) + j) * 4 + g];
      ge += __shfl_xor(ge, 4, 64);
      ge += __shfl_xor(ge, 8, 64);
      ge += __shfl_xor(ge, 16, 64);
      ge += __shfl_xor(ge, 32, 64);
      if (lane < 4) GA[w * 4 + lane] = ge;  // GA[g*8+j]
      __syncthreads();  // S1
      if (tid < 8) {
        const float gi = GA[tid], gf = GA[8 + tid], gg = GA[16 + tid], go = GA[24 + tid];
        const float c = sigf(gf) * ec + sigf(gi) * tanhf(gg);
        ec = c;
        const float h = sigf(go) * tanhf(c);
        st_bypass4(&ehbuf[(size_t)t * 1024 + (e << 3) + tid], h);  // coalesced 32B
      }
      int ok = 1;
      if (tid < 256) {
        const fv4 ev = poll2(&ehbuf[(size_t)t * 1024 + tid * 4], &ok);
        xbuf[tid] = make_float4(ev.x, ev.y, ev.z, ev.w);
      }
      if (!ok) sbad = 1;
      __syncthreads();  // S2
      if (sbad) break;
    }
  } else {
    // =========================== decoder group ===============================
    const int d = b - ENC_BLK;
    const int r = (g << 10) + (d << 3) + j;  // owned gate row
    float4 w1[16], wr[16];
#pragma unroll
    for (int k = 0; k < 16; k++) {
      const int m = (k + s16) & 15;
      w1[k] = *(const float4*)&Wihd[(size_t)r * 2048 + s16 * 64 + m * 4];
      const float4 a = *(const float4*)&Wihd[(size_t)r * 2048 + 1024 + s16 * 64 + m * 4];
      const float4 c = *(const float4*)&Whhd[(size_t)r * 1024 + s16 * 64 + m * 4];
      wr[k] = make_float4(a.x + c.x, a.y + c.y, a.z + c.z, a.w + c.w);
    }
    if (tid < 32) {
      const int gg2 = tid >> 3, jj2 = tid & 7;
      bd[tid] = bihd[(gg2 << 10) + (d << 3) + jj2] + bhhd[(gg2 << 10) + (d << 3) + jj2];
    }
    aw[tid] = 0.f;
    if (tid < 256) {
      xbuf[tid] = make_float4(0.f, 0.f, 0.f, 0.f);
      dbuf[tid] = make_float4(0.f, 0.f, 0.f, 0.f);
    }
    if (tid == 0) sbad = 0;
    float dc = 0.f;  // cell state (tid<8)
    float4 wo = make_float4(0.f, 0.f, 0.f, 0.f);
    if (tid < 256) wo = *(const float4*)&Wout[tid * 4];
    const float boutv = bout[0];
    __syncthreads();

    // loop-carried eh(t) speculative sample (compiler-managed in-flight).
    float es0 = 0.f, es1 = 0.f, es2 = 0.f, es3 = 0.f;
    if (tid < 256) {
      const float* pe = &ehbuf[(size_t)tid * 4];
      es0 = ld_f(pe + 0); es1 = ld_f(pe + 1); es2 = ld_f(pe + 2); es3 = ld_f(pe + 3);
    }

    bool failed = false;
    for (int t = 0; t < T_STEPS; t++) {
      // --- softmax partials over stale aw (overlaps in-flight eh samples) ---
      const float battn_t = battn[t];
      const float ex0 = expf(aw[tid]);  // aw in [0,1]: exp safe, no max needed
      float so = (tid == t) ? 0.f : ex0;
#pragma unroll
      for (int mk = 1; mk <= 32; mk <<= 1) so += __shfl_xor(so, mk, 64);
      if (lane == 0) red[w] = so;

      // --- consume eh(t): samples issued last iteration; wait mostly hidden ---
      float4 wae = make_float4(0.f, 0.f, 0.f, 0.f);
      float4 wad = make_float4(0.f, 0.f, 0.f, 0.f);
      float epe = 0.f;
      int ok1 = 1;
      if (tid < 256) {
        wae = *(const float4*)&Wattn[(size_t)t * 2048 + tid * 4];
        wad = *(const float4*)&Wattn[(size_t)t * 2048 + 1024 + tid * 4];
        fv4 ev;
        if (validf(es0, es1, es2, es3)) {
          ev.x = es0; ev.y = es1; ev.z = es2; ev.w = es3;
        } else {
          ev = poll2(&ehbuf[(size_t)t * 1024 + tid * 4], &ok1);
        }
        epe = wae.x * ev.x + wae.y * ev.y + wae.z * ev.z + wae.w * ev.w;
        xbuf[tid] = make_float4(ev.x, ev.y, ev.z, ev.w);
      }
      if (!ok1) sbad = 1;
#pragma unroll
      for (int mk = 1; mk <= 32; mk <<= 1) epe += __shfl_xor(epe, mk, 64);
      if (lane == 0 && w < 4) redE[w] = epe;
      __syncthreads();  // B1
      if (sbad) { failed = true; break; }

      // --- issue dh(t-1) speculative samples; g1 matvec covers the RTT ---
      float ds0 = 0.f, ds1 = 0.f, ds2 = 0.f, ds3 = 0.f;
      if (t > 0 && tid < 256) {
        const float* pd = &dhbuf[(size_t)(t - 1) * 1024 + tid * 4];
        ds0 = ld_f(pd + 0); ds1 = ld_f(pd + 1); ds2 = ld_f(pd + 2); ds3 = ld_f(pd + 3);
      }

      float g1 = 0.f;
#pragma unroll
      for (int k = 0; k < 16; k++) {
        const int m = (k + s16) & 15;
        const float4 x = xbuf[s16 * 16 + m];
        g1 += w1[k].x * x.x + w1[k].y * x.y + w1[k].z * x.z + w1[k].w * x.w;
      }
      g1 += __shfl_xor(g1, 4, 64);
      g1 += __shfl_xor(g1, 8, 64);
      g1 += __shfl_xor(g1, 16, 64);
      g1 += __shfl_xor(g1, 32, 64);
      if (lane < 4) GA[w * 4 + lane] = g1;

      // --- consume dh(t-1): the recurrence-critical wait ---
      float epd = 0.f;
      int ok2 = 1;
      if (t > 0 && tid < 256) {
        fv4 dv;
        if (validf(ds0, ds1, ds2, ds3)) {
          dv.x = ds0; dv.y = ds1; dv.z = ds2; dv.w = ds3;
        } else {
          dv = poll2(&dhbuf[(size_t)(t - 1) * 1024 + tid * 4], &ok2);
        }
        epd = wad.x * dv.x + wad.y * dv.y + wad.z * dv.z + wad.w * dv.w;
        dbuf[tid] = make_float4(dv.x, dv.y, dv.z, dv.w);
      }
      if (!ok2) sbad = 1;
#pragma unroll
      for (int mk = 1; mk <= 32; mk <<= 1) epd += __shfl_xor(epd, mk, 64);
      if (lane == 0 && w < 4) redE2[w] = epd;
      __syncthreads();  // B2
      if (sbad) { failed = true; break; }

      // --- g2 = (Wihd[:,H:]+Whhd) @ dh(t-1) ---
      float g2 = 0.f;
#pragma unroll
      for (int k = 0; k < 16; k++) {
        const int m = (k + s16) & 15;
        const float4 dd = dbuf[s16 * 16 + m];
        g2 += wr[k].x * dd.x + wr[k].y * dd.y + wr[k].z * dd.z + wr[k].w * dd.w;
      }
      g2 += __shfl_xor(g2, 4, 64);
      g2 += __shfl_xor(g2, 8, 64);
      g2 += __shfl_xor(g2, 16, 64);
      g2 += __shfl_xor(g2, 32, 64);
      if (lane < 4) GB[w * 4 + lane] = g2;

      // --- softmax finish (all threads redundantly) + aw update ---
      const float e_t = redE[0] + redE[1] + redE[2] + redE[3] +
                        redE2[0] + redE2[1] + redE2[2] + redE2[3] + battn_t;
      const float exden = expf(e_t);
      const float inv = 1.f / (red[0] + red[1] + red[2] + red[3] +
                               red[4] + red[5] + red[6] + red[7] + exden);
      const float awt = exden * inv;
      aw[tid] = ((tid == t) ? exden : ex0) * inv;
      __syncthreads();  // S3 (GA/GB ready)

      // --- decoder cell (tid<8) + coalesced publication ---
      if (tid < 8) {
        const float gi = awt * GA[tid]      + GB[tid]      + bd[tid];
        const float gf = awt * GA[8 + tid]  + GB[8 + tid]  + bd[8 + tid];
        const float gg = awt * GA[16 + tid] + GB[16 + tid] + bd[16 + tid];
        const float go = awt * GA[24 + tid] + GB[24 + tid] + bd[24 + tid];
        const float c = sigf(gf) * dc + sigf(gi) * tanhf(gg);
        dc = c;
        const float h = sigf(go) * tanhf(c);
        st_bypass4(&dhbuf[(size_t)t * 1024 + (d << 3) + tid], h);
      }

      // --- issue eh(t+1) speculative samples (in flight across back edge) ---
      if (tid < 256) {
        const int tn = (t + 1 < T_STEPS) ? (t + 1) : t;  // last iter: harmless
        const float* pe = &ehbuf[(size_t)tn * 1024 + tid * 4];
        es0 = ld_f(pe + 0); es1 = ld_f(pe + 1); es2 = ld_f(pe + 2); es3 = ld_f(pe + 3);
      }
    }

    // --- epilogue: out[t] = W_out·dh(t) + b_out, 4 t-values per block ---
    if (!failed) {
#pragma unroll
      for (int i = 0; i < 4; i++) {
        const int t = d * 4 + i;
        float op = 0.f;
        int ok = 1;
        if (tid < 256) {
          const fv4 dv = poll2(&dhbuf[(size_t)t * 1024 + tid * 4], &ok);
          op = wo.x * dv.x + wo.y * dv.y + wo.z * dv.z + wo.w * dv.w;
        }
        if (!ok) break;
#pragma unroll
        for (int mk = 1; mk <= 32; mk <<= 1) op += __shfl_xor(op, mk, 64);
        if (lane == 0 && w < 4) red2[w] = op;
        __syncthreads();
        if (tid == 0) out[t] = red2[0] + red2[1] + red2[2] + red2[3] + boutv;
        __syncthreads();
      }
    }
  }
}

// ---------------------------------- launch ------------------------------------
extern "C" void kernel_launch(void* const* d_in, const int* in_sizes, int n_in,
                              void* d_out, int out_size, void* d_ws, size_t ws_size,
                              hipStream_t stream) {
  const float* X     = (const float*)d_in[0];
  const float* Wihe  = (const float*)d_in[2];
  const float* Whhe  = (const float*)d_in[3];
  const float* bihe  = (const float*)d_in[4];
  const float* bhhe  = (const float*)d_in[5];
  const float* Wattn = (const float*)d_in[6];
  const float* battn = (const float*)d_in[7];
  const float* Wihd  = (const float*)d_in[8];
  const float* Whhd  = (const float*)d_in[9];
  const float* bihd  = (const float*)d_in[10];
  const float* bhhd  = (const float*)d_in[11];
  const float* Wo    = (const float*)d_in[12];
  const float* bo    = (const float*)d_in[13];
  float* out = (float*)d_out;

  float* ws    = (float*)d_ws;
  float* px    = ws;                                  // 512*1024*4 floats (8 MB)
  float* ehbuf = px + (size_t)T_STEPS * 1024 * 4;     // 512*1024 (2 MB)
  float* dhbuf = ehbuf + (size_t)T_STEPS * 1024;      // 512*1024 (2 MB)
  const size_t need = ((size_t)T_STEPS * 1024 * 6) * sizeof(float);
  if (ws_size < need) return;

  prep_gemm<<<dim3(64, 8), 256, 0, stream>>>(X, Wihe, bihe, bhhe, px);
  lstm_persist<<<NBLK, NTHR, 0, stream>>>(
      Whhe, Wattn, battn, Wihd, Whhd, bihd, bhhd, Wo, bo, px, ehbuf, dhbuf, out);
}